// Round 12
// baseline (3266.221 us; speedup 1.0000x reference)
//
#include <hip/hip_runtime.h>
#include <hip/hip_bf16.h>

typedef __hip_bfloat16 bf16;
typedef __bf16 bf16x8_t __attribute__((ext_vector_type(8)));
typedef float f32x4_t __attribute__((ext_vector_type(4)));
typedef float f32x16_t __attribute__((ext_vector_type(16)));
typedef unsigned short u16x8_t __attribute__((ext_vector_type(8)));

#define HID 3584
#define SEQ 2048
#define NBATCH 2
#define MTOK 4096
#define NHEADS 16
#define NKVH 8
#define HDIM 256
#define QOUT 4096
#define KOUT 2048
#define INTERD 14336
#define EPSF 1e-6f

static __device__ __forceinline__ unsigned short f2bu(float f) {
  union { bf16 b; unsigned short u; } cv;
  cv.b = __float2bfloat16(f);
  return cv.u;
}

static __device__ __forceinline__ f32x4_t mfma16(bf16x8_t a, bf16x8_t b, f32x4_t c) {
  return __builtin_amdgcn_mfma_f32_16x16x32_bf16(a, b, c, 0, 0, 0);
}

static __device__ __forceinline__ f32x16_t mfma32(bf16x8_t a, bf16x8_t b, f32x16_t c) {
  return __builtin_amdgcn_mfma_f32_32x32x16_bf16(a, b, c, 0, 0, 0);
}

static __device__ __forceinline__ void gl_lds16(const void* g, void* l) {
  __builtin_amdgcn_global_load_lds((__attribute__((address_space(1))) void*)g,
                                   (__attribute__((address_space(3))) void*)l,
                                   16, 0, 0);
}

static __device__ __forceinline__ float block_reduce_sum(float v) {
  __shared__ float buf[4];
  #pragma unroll
  for (int m = 1; m < 64; m <<= 1) v += __shfl_xor(v, m, 64);
  __syncthreads();
  if ((threadIdx.x & 63) == 0) buf[threadIdx.x >> 6] = v;
  __syncthreads();
  return buf[0] + buf[1] + buf[2] + buf[3];
}

// ---------------------------------------------------------------------------
// weight convert: f32 -> bf16
// ---------------------------------------------------------------------------
__global__ __launch_bounds__(256) void cvt_w(
    const float* __restrict__ src, bf16* __restrict__ dst, int n) {
  const int stride = gridDim.x * 256 * 8;
  for (int i = (blockIdx.x * 256 + threadIdx.x) * 8; i < n; i += stride) {
    const float4 a = *(const float4*)(src + i);
    const float4 b = *(const float4*)(src + i + 4);
    u16x8_t o;
    o[0] = f2bu(a.x); o[1] = f2bu(a.y); o[2] = f2bu(a.z); o[3] = f2bu(a.w);
    o[4] = f2bu(b.x); o[5] = f2bu(b.y); o[6] = f2bu(b.z); o[7] = f2bu(b.w);
    *(u16x8_t*)(dst + i) = o;
  }
}

// ---------------------------------------------------------------------------
// 128x128 GEMM on 32x32x16 MFMA (R12).
// R9-ablation (correctly read): only the {ds_read -> lgkm -> MFMA} dependency
// chain is slow (~280cyc per read-fed MFMA); all sync/stage components cheap.
// => cut dependency points 4x: per-wave 64x64 via 2x2 mfma_32x32x16 instead
// of 4x4 mfma_16x16x32. Skeleton = verified m97 form: single-buffered 16 KiB
// LDS, global_load_lds staging, plain __syncthreads, compiler-managed waits
// (no inline-asm waitcnt / setprio / sched_barrier anywhere in the loop).
// LDS [op][row128][k32] bf16, 64B rows; 16B-chunk swizzle c ^= (row>>2)&3
// (pre-swizzled global source; read side applies same XOR) -> ~4-way max.
// Natural 2D grid (no block swizzle; R2 measured lower FETCH without it).
// C/D layout (m74/m101): col = lane&31, row = (reg&3)+8*(reg>>2)+4*(lane>>5).
// ---------------------------------------------------------------------------
enum { EPI_BF16 = 0, EPI_F32 = 1, EPI_GELUMUL = 2, EPI_QK = 3, EPI_VSW = 4 };

template <int EPI>
__global__ __launch_bounds__(256) void gemm32(
    const bf16* __restrict__ A, const bf16* __restrict__ Bw,
    void* __restrict__ Cout, const bf16* __restrict__ aux,
    void* __restrict__ C2, int Ndim, int Kdim) {
  __shared__ __align__(16) bf16 As[128 * 32];
  __shared__ __align__(16) bf16 Bs[128 * 32];

  const int n0 = blockIdx.x * 128;
  const int m0 = blockIdx.y * 128;
  const int t = threadIdx.x;
  const int wid = t >> 6, l = t & 63;
  const int wm = wid >> 1, wn = wid & 1;
  const int lc = l & 31, lh = l >> 5;

  // staging: thread t -> LDS row t>>2, chunk t&3 (dest linear t*16 bytes);
  // global source chunk pre-swizzled: cS = ((t&3) ^ ((t>>4)&3)) * 8 elems.
  // (row+64 keeps the same (row>>2)&3 since 64>>2 == 0 mod 4.)
  const int rS = t >> 2;
  const int cS = (((t & 3) ^ ((t >> 4) & 3)) << 3);
  const bf16* Ab0 = A + (size_t)(m0 + rS) * Kdim + cS;
  const bf16* Ab1 = A + (size_t)(m0 + rS + 64) * Kdim + cS;
  const bf16* Bb0 = Bw + (size_t)(n0 + rS) * Kdim + cS;
  const bf16* Bb1 = Bw + (size_t)(n0 + rS + 64) * Kdim + cS;

  f32x16_t zz = {};
  f32x16_t acc[2][2] = {{zz, zz}, {zz, zz}};

  // fragment read geometry: row = w*64 + mi*32 + lc; 16B chunk index
  // (kc*2 + lh) ^ ((lc>>2)&3)  [(row>>2)&3 == (lc>>2)&3, offsets 0 mod 4].
  const int rsw = (lc >> 2) & 3;
  const int arow0 = (wm * 64 + lc) * 32;
  const int brow0 = (wn * 64 + lc) * 32;

  for (int kt = 0; kt < Kdim; kt += 32) {
    __syncthreads();  // prior iteration's fragment reads done before overwrite
    gl_lds16(Ab0 + kt, (char*)As + t * 16);
    gl_lds16(Ab1 + kt, (char*)As + 4096 + t * 16);
    gl_lds16(Bb0 + kt, (char*)Bs + t * 16);
    gl_lds16(Bb1 + kt, (char*)Bs + 4096 + t * 16);
    __syncthreads();  // staging complete (drains vmcnt/lgkm)

    #pragma unroll
    for (int kc = 0; kc < 2; kc++) {
      const int ch = (((kc << 1) + lh) ^ rsw) << 3;  // elem offset in row
      bf16x8_t fa0 = *(const bf16x8_t*)(As + arow0 + ch);
      bf16x8_t fa1 = *(const bf16x8_t*)(As + arow0 + 32 * 32 + ch);
      bf16x8_t fb0 = *(const bf16x8_t*)(Bs + brow0 + ch);
      bf16x8_t fb1 = *(const bf16x8_t*)(Bs + brow0 + 32 * 32 + ch);
      acc[0][0] = mfma32(fa0, fb0, acc[0][0]);
      acc[0][1] = mfma32(fa0, fb1, acc[0][1]);
      acc[1][0] = mfma32(fa1, fb0, acc[1][0]);
      acc[1][1] = mfma32(fa1, fb1, acc[1][1]);
    }
  }

  // Epilogue. 32x32 C/D: col = lane&31, row = (reg&3) + 8*(reg>>2) + 4*lh.
  const int colb = n0 + wn * 64 + lc;
  const int rowb = m0 + wm * 64 + 4 * lh;
  #pragma unroll
  for (int mi = 0; mi < 2; mi++) {
    #pragma unroll
    for (int ni = 0; ni < 2; ni++) {
      #pragma unroll
      for (int reg = 0; reg < 16; reg++) {
        const int row = rowb + mi * 32 + (reg & 3) + 8 * (reg >> 2);
        const int col = colb + ni * 32;
        const float v = acc[mi][ni][reg];
        if constexpr (EPI == EPI_BF16) {
          ((bf16*)Cout)[(size_t)row * Ndim + col] = __float2bfloat16(v);
        } else if constexpr (EPI == EPI_F32) {
          ((float*)Cout)[(size_t)row * Ndim + col] = v;
        } else if constexpr (EPI == EPI_QK) {
          // cols [0,4096) -> q; [4096,6144) -> k (both row-major).
          if (col < 4096) {
            ((bf16*)Cout)[(size_t)row * 4096 + col] = __float2bfloat16(v);
          } else {
            ((bf16*)C2)[(size_t)row * 2048 + (col - 4096)] =
                __float2bfloat16(v);
          }
        } else if constexpr (EPI == EPI_VSW) {
          // swapped V GEMM: row = kv-dim (kvh*256+d), col = token (b*2048+s).
          const int bb = col >> 11, s = col & 2047;
          ((bf16*)Cout)[(((size_t)((bb * 8 + (row >> 8)) * 256 + (row & 255)))
                         << 11) + s] = __float2bfloat16(v);
        } else {  // EPI_GELUMUL
          const float g = __bfloat162float(aux[(size_t)row * Ndim + col]);
          const float u = 0.7978845608028654f * (g + 0.044715f * g * g * g);
          const float gl = 0.5f * g * (1.f + tanhf(u));
          ((bf16*)Cout)[(size_t)row * Ndim + col] = __float2bfloat16(gl * v);
        }
      }
    }
  }
  (void)aux; (void)C2;
}

// ---------------------------------------------------------------------------
// RMSNorm of input hidden -> bf16
// ---------------------------------------------------------------------------
__global__ __launch_bounds__(256) void rmsnorm_in(
    const float* __restrict__ x, const float* __restrict__ w,
    bf16* __restrict__ out) {
  const int row = blockIdx.x, t = threadIdx.x;
  const float4* xr = (const float4*)(x + (size_t)row * HID);
  float4 v[4];
  float ss = 0.f;
  #pragma unroll
  for (int j = 0; j < 4; j++) {
    const int idx = t + 256 * j;
    if (idx < HID / 4) {
      v[j] = xr[idx];
      ss += v[j].x * v[j].x + v[j].y * v[j].y + v[j].z * v[j].z + v[j].w * v[j].w;
    }
  }
  ss = block_reduce_sum(ss);
  const float sc = rsqrtf(ss * (1.f / HID) + EPSF);
  const float4* w4 = (const float4*)w;
  bf16* orow = out + (size_t)row * HID;
  #pragma unroll
  for (int j = 0; j < 4; j++) {
    const int idx = t + 256 * j;
    if (idx < HID / 4) {
      const float4 wv = w4[idx];
      ushort4 o;
      o.x = f2bu(v[j].x * sc * (1.f + wv.x));
      o.y = f2bu(v[j].y * sc * (1.f + wv.y));
      o.z = f2bu(v[j].z * sc * (1.f + wv.z));
      o.w = f2bu(v[j].w * sc * (1.f + wv.w));
      *(ushort4*)(orow + idx * 4) = o;
    }
  }
}

// ---------------------------------------------------------------------------
// RoPE in-place on q (16 heads) and k (8 heads), bf16.
// ---------------------------------------------------------------------------
__global__ __launch_bounds__(128) void rope_kernel(
    bf16* __restrict__ q, bf16* __restrict__ k,
    const float* __restrict__ cosb, const float* __restrict__ sinb) {
  const int tok = blockIdx.x;
  const int hs = blockIdx.y;
  const int d = threadIdx.x;
  const int s = tok & (SEQ - 1);
  bf16* ptr = (hs < NHEADS)
                  ? q + (size_t)tok * QOUT + hs * HDIM
                  : k + (size_t)tok * KOUT + (hs - NHEADS) * HDIM;
  const float c = cosb[s * HDIM + d];
  const float sn = sinb[s * HDIM + d];
  const float x0 = __bfloat162float(ptr[d]);
  const float x1 = __bfloat162float(ptr[d + 128]);
  ptr[d] = __float2bfloat16(x0 * c - x1 * sn);
  ptr[d + 128] = __float2bfloat16(x1 * c + x0 * sn);
}

// ---------------------------------------------------------------------------
// Flash attention, sliding window 1024, softcap 50, fixed-base softmax.
// ---------------------------------------------------------------------------
__global__ __launch_bounds__(256) void attn_kernel(
    const bf16* __restrict__ q, const bf16* __restrict__ k,
    const bf16* __restrict__ vt, bf16* __restrict__ out) {
  __shared__ __align__(16) bf16 plds[4][16 * 32];

  const int qt = blockIdx.x, h = blockIdx.y, b = blockIdx.z;
  const int w = threadIdx.x >> 6, l = threadIdx.x & 63;
  const int kvh = h >> 1;
  const int qbase = qt * 64 + w * 16;
  const int lr = l & 15, lg = l >> 4, lk = lg * 8;

  bf16x8_t qf[8];
  const bf16* qrow = q + (size_t)(b * SEQ + qbase + lr) * QOUT + h * HDIM;
  #pragma unroll
  for (int c = 0; c < 8; c++) qf[c] = *(const bf16x8_t*)(qrow + c * 32 + lk);

  f32x4_t acc[16];
  #pragma unroll
  for (int i = 0; i < 16; i++) acc[i] = (f32x4_t){0.f, 0.f, 0.f, 0.f};
  float L[4] = {0.f, 0.f, 0.f, 0.f};

  const bf16* kp = k + (size_t)(b * SEQ) * KOUT + kvh * HDIM;
  const bf16* vp = vt + (size_t)(b * NKVH + kvh) * HDIM * SEQ;
  bf16* pl = &plds[w][0];

  int kstart = qbase - 1023;
  if (kstart < 0) kstart = 0;
  kstart &= ~31;
  const int kend = qbase + 15;

  for (int kb = kstart; kb <= kend; kb += 32) {
    f32x4_t s0 = (f32x4_t){0.f, 0.f, 0.f, 0.f};
    f32x4_t s1 = (f32x4_t){0.f, 0.f, 0.f, 0.f};
    #pragma unroll
    for (int c = 0; c < 8; c++) {
      bf16x8_t k0 = *(const bf16x8_t*)(kp + (size_t)(kb + lr) * KOUT + c * 32 + lk);
      bf16x8_t k1 = *(const bf16x8_t*)(kp + (size_t)(kb + 16 + lr) * KOUT + c * 32 + lk);
      s0 = mfma16(qf[c], k0, s0);
      s1 = mfma16(qf[c], k1, s1);
    }
    float p[8];
    #pragma unroll
    for (int sub = 0; sub < 2; sub++) {
      const int j = kb + sub * 16 + lr;
      #pragma unroll
      for (int r = 0; r < 4; r++) {
        const int i = qbase + lg * 4 + r;
        float sc = (sub ? s1[r] : s0[r]) * 0.0625f;
        sc = 50.f * tanhf(sc * 0.02f);
        const bool ok = (j <= i) && (j > i - 1024);
        p[sub * 4 + r] = ok ? __expf(sc) : 0.f;
      }
    }
    #pragma unroll
    for (int r = 0; r < 4; r++) {
      float ps = p[r] + p[4 + r];
      ps += __shfl_xor(ps, 1, 64);
      ps += __shfl_xor(ps, 2, 64);
      ps += __shfl_xor(ps, 4, 64);
      ps += __shfl_xor(ps, 8, 64);
      L[r] += ps;
    }
    #pragma unroll
    for (int sub = 0; sub < 2; sub++)
      #pragma unroll
      for (int r = 0; r < 4; r++)
        pl[(lg * 4 + r) * 32 + sub * 16 + lr] = __float2bfloat16(p[sub * 4 + r]);
    asm volatile("s_waitcnt lgkmcnt(0)" ::: "memory");
    const bf16x8_t pa = *(const bf16x8_t*)(pl + lr * 32 + lk);
    #pragma unroll
    for (int dt = 0; dt < 16; dt++) {
      bf16x8_t bv = *(const bf16x8_t*)(vp + (size_t)(dt * 16 + lr) * SEQ + kb + lk);
      acc[dt] = mfma16(pa, bv, acc[dt]);
    }
  }

  float rL[4];
  #pragma unroll
  for (int r = 0; r < 4; r++) rL[r] = 1.f / L[r];
  #pragma unroll
  for (int dt = 0; dt < 16; dt++) {
    #pragma unroll
    for (int r = 0; r < 4; r++) {
      const int tok = b * SEQ + qbase + lg * 4 + r;
      out[(size_t)tok * QOUT + h * HDIM + dt * 16 + lr] =
          __float2bfloat16(acc[dt][r] * rL[r]);
    }
  }
}

// ---------------------------------------------------------------------------
// fuse1: h1 = hidden + rmsnorm(attn_proj, w_post); y = bf16(rmsnorm(h1, w_pre))
// ---------------------------------------------------------------------------
__global__ __launch_bounds__(256) void fuse_attn(
    const float* __restrict__ hidden, const float* __restrict__ ap,
    const float* __restrict__ w_post, const float* __restrict__ w_pre,
    float* __restrict__ h1, bf16* __restrict__ y) {
  const int row = blockIdx.x, t = threadIdx.x;
  const float4* ar = (const float4*)(ap + (size_t)row * HID);
  const float4* hr = (const float4*)(hidden + (size_t)row * HID);
  float4 a[4];
  float ss = 0.f;
  #pragma unroll
  for (int j = 0; j < 4; j++) {
    const int idx = t + 256 * j;
    if (idx < HID / 4) {
      a[j] = ar[idx];
      ss += a[j].x * a[j].x + a[j].y * a[j].y + a[j].z * a[j].z + a[j].w * a[j].w;
    }
  }
  ss = block_reduce_sum(ss);
  const float sc = rsqrtf(ss * (1.f / HID) + EPSF);
  const float4* wpo = (const float4*)w_post;
  float4* h1r = (float4*)(h1 + (size_t)row * HID);
  float4 hv[4];
  float ss2 = 0.f;
  #pragma unroll
  for (int j = 0; j < 4; j++) {
    const int idx = t + 256 * j;
    if (idx < HID / 4) {
      const float4 wv = wpo[idx];
      const float4 x = hr[idx];
      hv[j].x = x.x + a[j].x * sc * (1.f + wv.x);
      hv[j].y = x.y + a[j].y * sc * (1.f + wv.y);
      hv[j].z = x.z + a[j].z * sc * (1.f + wv.z);
      hv[j].w = x.w + a[j].w * sc * (1.f + wv.w);
      ss2 += hv[j].x * hv[j].x + hv[j].y * hv[j].y + hv[j].z * hv[j].z + hv[j].w * hv[j].w;
      h1r[idx] = hv[j];
    }
  }
  ss2 = block_reduce_sum(ss2);
  const float sc2 = rsqrtf(ss2 * (1.f / HID) + EPSF);
  const float4* wpr = (const float4*)w_pre;
  bf16* yr = y + (size_t)row * HID;
  #pragma unroll
  for (int j = 0; j < 4; j++) {
    const int idx = t + 256 * j;
    if (idx < HID / 4) {
      const float4 wv = wpr[idx];
      ushort4 o;
      o.x = f2bu(hv[j].x * sc2 * (1.f + wv.x));
      o.y = f2bu(hv[j].y * sc2 * (1.f + wv.y));
      o.z = f2bu(hv[j].z * sc2 * (1.f + wv.z));
      o.w = f2bu(hv[j].w * sc2 * (1.f + wv.w));
      *(ushort4*)(yr + idx * 4) = o;
    }
  }
}

// ---------------------------------------------------------------------------
// fuse2: out = h1 + rmsnorm(mlp, w_post_ff)
// ---------------------------------------------------------------------------
__global__ __launch_bounds__(256) void fuse_out(
    const float* __restrict__ h1, const float* __restrict__ mlp,
    const float* __restrict__ w, float* __restrict__ out) {
  const int row = blockIdx.x, t = threadIdx.x;
  const float4* mr = (const float4*)(mlp + (size_t)row * HID);
  float4 m[4];
  float ss = 0.f;
  #pragma unroll
  for (int j = 0; j < 4; j++) {
    const int idx = t + 256 * j;
    if (idx < HID / 4) {
      m[j] = mr[idx];
      ss += m[j].x * m[j].x + m[j].y * m[j].y + m[j].z * m[j].z + m[j].w * m[j].w;
    }
  }
  ss = block_reduce_sum(ss);
  const float sc = rsqrtf(ss * (1.f / HID) + EPSF);
  const float4* hr = (const float4*)(h1 + (size_t)row * HID);
  const float4* w4 = (const float4*)w;
  float4* orow = (float4*)(out + (size_t)row * HID);
  #pragma unroll
  for (int j = 0; j < 4; j++) {
    const int idx = t + 256 * j;
    if (idx < HID / 4) {
      const float4 wv = w4[idx];
      const float4 x = hr[idx];
      float4 o;
      o.x = x.x + m[j].x * sc * (1.f + wv.x);
      o.y = x.y + m[j].y * sc * (1.f + wv.y);
      o.z = x.z + m[j].z * sc * (1.f + wv.z);
      o.w = x.w + m[j].w * sc * (1.f + wv.w);
      orow[idx] = o;
    }
  }
}

// ---------------------------------------------------------------------------
extern "C" void kernel_launch(void* const* d_in, const int* in_sizes, int n_in,
                              void* d_out, int out_size, void* d_ws,
                              size_t ws_size, hipStream_t stream) {
  const float* hidden = (const float*)d_in[0];
  const float* cosb = (const float*)d_in[1];
  const float* sinb = (const float*)d_in[2];
  const float* Wq = (const float*)d_in[3];
  const float* Wk = (const float*)d_in[4];
  const float* Wv = (const float*)d_in[5];
  const float* Wo = (const float*)d_in[6];
  const float* Wgate = (const float*)d_in[7];
  const float* Wup = (const float*)d_in[8];
  const float* Wdown = (const float*)d_in[9];
  const float* w_in = (const float*)d_in[10];
  const float* w_post_attn = (const float*)d_in[11];
  const float* w_pre_ff = (const float*)d_in[12];
  const float* w_post_ff = (const float*)d_in[13];
  float* out = (float*)d_out;

  (void)in_sizes; (void)n_in; (void)out_size; (void)ws_size;

  const size_t WB = 102760448;  // 14336*3584*2 — bf16 weight scratch
  char* ws = (char*)d_ws;
  bf16* wbuf = (bf16*)ws;
  char* ab = ws + WB;

  bf16* xn = (bf16*)(ab);
  bf16* q = (bf16*)(ab + 29360128);
  float* attn_proj = (float*)(ab);
  float* mlp = (float*)(ab);
  bf16* kbuf = (bf16*)(ab + 62914560);
  bf16* vt = (bf16*)(ab + 62914560 + 16777216);
  bf16* attn_out = (bf16*)(ab + 62914560 + 33554432);
  float* h1 = (float*)(ab + 62914560);
  bf16* y = (bf16*)(ab + 130023424);
  bf16* gate = (bf16*)(ab + 159383552);

  rmsnorm_in<<<MTOK, 256, 0, stream>>>(hidden, w_in, xn);

  // wbuf rows [0,4096)=Wq, [4096,6144)=Wk, [6144,8192)=Wv
  cvt_w<<<4096, 256, 0, stream>>>(Wq, wbuf, QOUT * HID);
  cvt_w<<<2048, 256, 0, stream>>>(Wk, wbuf + (size_t)QOUT * HID, KOUT * HID);
  cvt_w<<<2048, 256, 0, stream>>>(Wv, wbuf + (size_t)(QOUT + KOUT) * HID,
                                  KOUT * HID);
  gemm32<EPI_QK><<<dim3(6144 / 128, MTOK / 128), 256, 0, stream>>>(
      xn, wbuf, q, nullptr, kbuf, 6144, HID);
  gemm32<EPI_VSW><<<dim3(MTOK / 128, KOUT / 128), 256, 0, stream>>>(
      wbuf + (size_t)(QOUT + KOUT) * HID, xn, vt, nullptr, nullptr,
      MTOK, HID);
  rope_kernel<<<dim3(MTOK, NHEADS + NKVH), 128, 0, stream>>>(q, kbuf, cosb, sinb);
  attn_kernel<<<dim3(SEQ / 64, NHEADS, NBATCH), 256, 0, stream>>>(
      q, kbuf, vt, attn_out);
  cvt_w<<<4096, 256, 0, stream>>>(Wo, wbuf, HID * QOUT);
  gemm32<EPI_F32><<<dim3(HID / 128, MTOK / 128), 256, 0, stream>>>(
      attn_out, wbuf, attn_proj, nullptr, nullptr, HID, QOUT);
  fuse_attn<<<MTOK, 256, 0, stream>>>(hidden, attn_proj, w_post_attn,
                                      w_pre_ff, h1, y);
  cvt_w<<<4096, 256, 0, stream>>>(Wgate, wbuf, INTERD * HID);
  gemm32<EPI_BF16><<<dim3(INTERD / 128, MTOK / 128), 256, 0, stream>>>(
      y, wbuf, gate, nullptr, nullptr, INTERD, HID);
  cvt_w<<<4096, 256, 0, stream>>>(Wup, wbuf, INTERD * HID);
  gemm32<EPI_GELUMUL><<<dim3(INTERD / 128, MTOK / 128), 256, 0, stream>>>(
      y, wbuf, gate, gate, nullptr, INTERD, HID);
  cvt_w<<<4096, 256, 0, stream>>>(Wdown, wbuf, INTERD * HID);
  gemm32<EPI_F32><<<dim3(HID / 128, MTOK / 128), 256, 0, stream>>>(
      gate, wbuf, mlp, nullptr, nullptr, HID, INTERD);

  fuse_out<<<MTOK, 256, 0, stream>>>(h1, mlp, w_post_ff, out);
}